// Round 4
// baseline (572.963 us; speedup 1.0000x reference)
//
#include <hip/hip_runtime.h>
#include <hip/hip_bf16.h>

#define BB 64
#define SS 4096
#define HH 256
#define AA 128

typedef _Float16 half8v __attribute__((ext_vector_type(8)));
typedef float floatx16 __attribute__((ext_vector_type(16)));

__device__ __forceinline__ float fast_tanh(float x) {
    float xc = fminf(fmaxf(x, -9.0f), 9.0f);
    float e = __expf(2.0f * xc);
    return 1.0f - __fdividef(2.0f, e + 1.0f);
}

// ---------------------------------------------------------------------------
// K0: W1 [H=256][A=128] fp32  ->  Wt [A=128][H=256] f16 (transposed) in d_ws
// ---------------------------------------------------------------------------
__global__ void convert_w1(const float* __restrict__ W1, _Float16* __restrict__ Wt) {
    int n = blockIdx.x;    // 0..127 (A)
    int k = threadIdx.x;   // 0..255 (H)
    Wt[n * HH + k] = (_Float16)W1[k * AA + n];
}

// ---------------------------------------------------------------------------
// K1: scores = tanh(X@W1 + b1)@W2 + b2 — K-split streaming MFMA.
// Block = 4 waves, owns 32 rows. Wave w owns K-slice [64w, 64w+64):
//   B-frags for its slice = 4nt x 4k x 4 VGPRs = 64 VGPRs, preloaded ONCE.
//   Main loop: 8 independent A float4 loads (hoisted) -> cvt -> 16 MFMAs.
// Partial sums exchanged via LDS (one barrier), tanh/W2 epilogue fused.
// C layout (32x32): col=lane&31, row=(r&3)+8*(r>>2)+4*(lane>>5)  [verified].
// ---------------------------------------------------------------------------
__global__ __launch_bounds__(256, 2) void score_ksplit(
    const float* __restrict__ X,        // [B*S, H]
    const _Float16* __restrict__ Wt,    // [A, H] f16
    const float* __restrict__ b1,       // [A]
    const float* __restrict__ W2,       // [A]
    const float* __restrict__ b2,       // [1]
    float* __restrict__ scores)         // [B*S]
{
    __shared__ float xch[4][3][64][16];   // 48 KB: [dst_wave][slot][lane][16]
    __shared__ float red[4][32];

    const int tid   = threadIdx.x;
    const int wid   = tid >> 6;
    const int lane  = tid & 63;
    const int lrow  = lane & 31;
    const int lhalf = lane >> 5;
    const int m0    = blockIdx.x * 32;
    const int kbase = wid * 64;           // this wave's K-slice

    // --- preload B fragments for this wave's K-slice (64 VGPRs) ---
    half8v bf[4][4];
    #pragma unroll
    for (int nt = 0; nt < 4; ++nt)
        #pragma unroll
        for (int k2 = 0; k2 < 4; ++k2)
            bf[nt][k2] = *(const half8v*)(Wt + (size_t)(nt * 32 + lrow) * HH
                                          + kbase + k2 * 16 + lhalf * 8);

    floatx16 acc[4];
    #pragma unroll
    for (int nt = 0; nt < 4; ++nt)
        #pragma unroll
        for (int r = 0; r < 16; ++r) acc[nt][r] = 0.0f;

    // --- main loop: stream A, 16 MFMAs total ---
    const float* xp = X + (size_t)(m0 + lrow) * HH + kbase + lhalf * 8;
    #pragma unroll
    for (int k2 = 0; k2 < 4; ++k2) {
        float4 v0 = *(const float4*)(xp + k2 * 16);
        float4 v1 = *(const float4*)(xp + k2 * 16 + 4);
        half8v a;
        a[0] = (_Float16)v0.x; a[1] = (_Float16)v0.y;
        a[2] = (_Float16)v0.z; a[3] = (_Float16)v0.w;
        a[4] = (_Float16)v1.x; a[5] = (_Float16)v1.y;
        a[6] = (_Float16)v1.z; a[7] = (_Float16)v1.w;
        #pragma unroll
        for (int nt = 0; nt < 4; ++nt)
            acc[nt] = __builtin_amdgcn_mfma_f32_32x32x16_f16(a, bf[nt][k2], acc[nt], 0, 0, 0);
    }

    // --- cross-wave partial-sum exchange: wave w keeps nt==w, ships others ---
    #pragma unroll
    for (int nt = 0; nt < 4; ++nt) {
        if (nt != wid) {
            int slot = (wid - nt - 1) & 3;   // 0..2
            float* dst = &xch[nt][slot][lane][0];
            #pragma unroll
            for (int q = 0; q < 4; ++q) {
                float4 v;
                v.x = acc[nt][q * 4 + 0]; v.y = acc[nt][q * 4 + 1];
                v.z = acc[nt][q * 4 + 2]; v.w = acc[nt][q * 4 + 3];
                *(float4*)(dst + q * 4) = v;
            }
        }
    }
    __syncthreads();

    floatx16 tot = acc[wid];
    #pragma unroll
    for (int s = 0; s < 3; ++s) {
        const float* src = &xch[wid][s][lane][0];
        #pragma unroll
        for (int q = 0; q < 4; ++q) {
            float4 v = *(const float4*)(src + q * 4);
            tot[q * 4 + 0] += v.x; tot[q * 4 + 1] += v.y;
            tot[q * 4 + 2] += v.z; tot[q * 4 + 3] += v.w;
        }
    }

    // --- epilogue: tanh + dot(W2) over this wave's 32 cols, row-reduce ---
    const int col = wid * 32 + lrow;
    const float c1 = b1[col], c2 = W2[col];
    #pragma unroll
    for (int r = 0; r < 16; ++r) {
        float v = fast_tanh(tot[r] + c1) * c2;
        #pragma unroll
        for (int o = 1; o < 32; o <<= 1) v += __shfl_xor(v, o);  // halves independent
        if (lrow == 0)
            red[wid][(r & 3) + 8 * (r >> 2) + 4 * lhalf] = v;
    }
    __syncthreads();
    if (tid < 32)
        scores[m0 + tid] = b2[0] + red[0][tid] + red[1][tid] + red[2][tid] + red[3][tid];
}

// ---------------------------------------------------------------------------
// K2: entmax-1.5 over S per batch row via bisection on tau.
// In-place scores -> weights; zero-inits ctx.
// ---------------------------------------------------------------------------
__global__ __launch_bounds__(256) void entmax_kernel(
    float* __restrict__ buf, float* __restrict__ ctx)
{
    __shared__ float sred[4];
    const int b = blockIdx.x, tid = threadIdx.x;
    float* p = buf + (size_t)b * SS;

    float z[16];
    #pragma unroll
    for (int j = 0; j < 16; ++j) z[j] = p[tid + j * 256] * 0.5f;

    float m = -1e30f;
    #pragma unroll
    for (int j = 0; j < 16; ++j) m = fmaxf(m, z[j]);
    #pragma unroll
    for (int o = 1; o < 64; o <<= 1) m = fmaxf(m, __shfl_xor(m, o));
    if ((tid & 63) == 0) sred[tid >> 6] = m;
    __syncthreads();
    m = fmaxf(fmaxf(sred[0], sred[1]), fmaxf(sred[2], sred[3]));
    __syncthreads();
    #pragma unroll
    for (int j = 0; j < 16; ++j) z[j] -= m;

    float lo = -1.0f, hi = 0.0f;
    for (int it = 0; it < 35; ++it) {
        float tau = 0.5f * (lo + hi);
        float s = 0.0f;
        #pragma unroll
        for (int j = 0; j < 16; ++j) {
            float d = fmaxf(z[j] - tau, 0.0f);
            s = fmaf(d, d, s);
        }
        #pragma unroll
        for (int o = 1; o < 64; o <<= 1) s += __shfl_xor(s, o);
        if ((tid & 63) == 0) sred[tid >> 6] = s;
        __syncthreads();
        s = sred[0] + sred[1] + sred[2] + sred[3];
        __syncthreads();
        if (s >= 1.0f) lo = tau; else hi = tau;
    }
    const float tau = 0.5f * (lo + hi);

    #pragma unroll
    for (int j = 0; j < 16; ++j) {
        float d = fmaxf(z[j] - tau, 0.0f);
        p[tid + j * 256] = d * d;
    }
    ctx[b * HH + tid] = 0.0f;
}

// ---------------------------------------------------------------------------
// K3: context[b,h] += sum_s X[b,s,h] * w[b,s]; entmax sparsity -> skip zeros
// ---------------------------------------------------------------------------
__global__ __launch_bounds__(256) void context_kernel(
    const float* __restrict__ X, const float* __restrict__ w,
    float* __restrict__ ctx)
{
    const int b  = blockIdx.y;
    const int s0 = blockIdx.x * 128;
    const int h  = threadIdx.x;

    __shared__ float ws_[128];
    __shared__ int nzflag;
    if (h == 0) nzflag = 0;
    __syncthreads();
    if (h < 128) {
        float v = w[(size_t)b * SS + s0 + h];
        ws_[h] = v;
        if (v > 0.0f) nzflag = 1;
    }
    __syncthreads();
    if (!nzflag) return;

    float acc = 0.0f;
    const float* xp = X + ((size_t)b * SS + s0) * HH + h;
    #pragma unroll 4
    for (int i = 0; i < 128; ++i) {
        float wv = ws_[i];
        if (wv != 0.0f) acc = fmaf(xp[(size_t)i * HH], wv, acc);
    }
    atomicAdd(&ctx[b * HH + h], acc);
}

extern "C" void kernel_launch(void* const* d_in, const int* in_sizes, int n_in,
                              void* d_out, int out_size, void* d_ws, size_t ws_size,
                              hipStream_t stream) {
    const float* X  = (const float*)d_in[0];
    const float* W1 = (const float*)d_in[1];
    const float* b1 = (const float*)d_in[2];
    const float* W2 = (const float*)d_in[3];
    const float* b2 = (const float*)d_in[4];

    float* out = (float*)d_out;
    float* ctx = out;            // [64*256]
    float* wts = out + BB * HH;  // [64*4096] scores -> weights
    _Float16* Wt = (_Float16*)d_ws;  // [128][256] f16, 64 KB

    convert_w1<<<AA, HH, 0, stream>>>(W1, Wt);
    score_ksplit<<<(BB * SS) / 32, 256, 0, stream>>>(X, Wt, b1, W2, b2, wts);
    entmax_kernel<<<BB, 256, 0, stream>>>(wts, ctx);
    context_kernel<<<dim3(SS / 128, BB), 256, 0, stream>>>(X, wts, ctx);
}

// Round 5
// 502.392 us; speedup vs baseline: 1.1405x; 1.1405x over previous
//
#include <hip/hip_runtime.h>
#include <hip/hip_bf16.h>

#define BB 64
#define SS 4096
#define HH 256
#define AA 128

typedef _Float16 half8v __attribute__((ext_vector_type(8)));
typedef float floatx16 __attribute__((ext_vector_type(16)));

__device__ __forceinline__ float fast_tanh(float x) {
    float xc = fminf(fmaxf(x, -9.0f), 9.0f);
    float e = __expf(2.0f * xc);
    return 1.0f - __fdividef(2.0f, e + 1.0f);
}

// ---------------------------------------------------------------------------
// K0: W1 [H=256][A=128] fp32  ->  Wt [A=128][H=256] f16 (transposed) in d_ws
// ---------------------------------------------------------------------------
__global__ void convert_w1(const float* __restrict__ W1, _Float16* __restrict__ Wt) {
    int n = blockIdx.x;    // 0..127 (A)
    int k = threadIdx.x;   // 0..255 (H)
    Wt[n * HH + k] = (_Float16)W1[k * AA + n];
}

// ---------------------------------------------------------------------------
// K1: scores = tanh(X@W1 + b1)@W2 + b2 — N-split streaming MFMA.
// Block = 4 waves, owns 32 rows of X. Wave w owns cols [32w, 32w+32) with the
// FULL K=256: B-tile = 32x256 f16 / 64 lanes = 64 VGPRs, preloaded once with
// compile-time indices (no dynamic reg-array indexing -> no scratch spill).
// Main loop: 16 unrolled k-steps {2 independent float4 A loads, pk-cvt,
// 1 MFMA into a single floatx16 acc}. Zero barriers until the final 512 B
// LDS combine. All 4 waves read identical A addresses -> L1 broadcast.
// A layout: m=lane&31, k=(lane>>5)*8+j.  B layout: n=lane&31, k=(lane>>5)*8+j.
// C layout (32x32): col=lane&31, row=(r&3)+8*(r>>2)+4*(lane>>5)  [verified].
// ---------------------------------------------------------------------------
__global__ __launch_bounds__(256) void score_nsplit(
    const float* __restrict__ X,        // [B*S, H]
    const _Float16* __restrict__ Wt,    // [A, H] f16
    const float* __restrict__ b1,       // [A]
    const float* __restrict__ W2,       // [A]
    const float* __restrict__ b2,       // [1]
    float* __restrict__ scores)         // [B*S]
{
    __shared__ float red[4][32];

    const int tid   = threadIdx.x;
    const int wid   = tid >> 6;
    const int lane  = tid & 63;
    const int lrow  = lane & 31;
    const int lhalf = lane >> 5;
    const int m0    = blockIdx.x * 32;
    const int col0  = wid * 32;

    // --- preload this wave's B-tile: 32 cols x K=256 (64 VGPRs) ---
    const _Float16* wp = Wt + (size_t)(col0 + lrow) * HH + lhalf * 8;
    half8v bf[16];
    #pragma unroll
    for (int k2 = 0; k2 < 16; ++k2)
        bf[k2] = *(const half8v*)(wp + k2 * 16);

    floatx16 acc;
    #pragma unroll
    for (int r = 0; r < 16; ++r) acc[r] = 0.0f;

    // --- main loop: stream A from global, cvt, MFMA ---
    const float* xp = X + (size_t)(m0 + lrow) * HH + lhalf * 8;
    #pragma unroll
    for (int k2 = 0; k2 < 16; ++k2) {
        float4 v0 = *(const float4*)(xp + k2 * 16);
        float4 v1 = *(const float4*)(xp + k2 * 16 + 4);
        half8v a;
        a[0] = (_Float16)v0.x; a[1] = (_Float16)v0.y;
        a[2] = (_Float16)v0.z; a[3] = (_Float16)v0.w;
        a[4] = (_Float16)v1.x; a[5] = (_Float16)v1.y;
        a[6] = (_Float16)v1.z; a[7] = (_Float16)v1.w;
        acc = __builtin_amdgcn_mfma_f32_32x32x16_f16(a, bf[k2], acc, 0, 0, 0);
    }

    // --- epilogue: tanh + dot(W2) over this wave's 32 cols ---
    const int col = col0 + lrow;
    const float c1 = b1[col], c2 = W2[col];
    #pragma unroll
    for (int r = 0; r < 16; ++r) {
        float v = fast_tanh(acc[r] + c1) * c2;
        #pragma unroll
        for (int o = 1; o < 32; o <<= 1) v += __shfl_xor(v, o);  // 32-halves independent
        if (lrow == 0)
            red[wid][(r & 3) + 8 * (r >> 2) + 4 * lhalf] = v;
    }
    __syncthreads();
    if (tid < 32)
        scores[m0 + tid] = b2[0] + red[0][tid] + red[1][tid] + red[2][tid] + red[3][tid];
}

// ---------------------------------------------------------------------------
// K2: entmax-1.5 over S per batch row via bisection on tau.
// In-place scores -> weights; zero-inits ctx.
// ---------------------------------------------------------------------------
__global__ __launch_bounds__(256) void entmax_kernel(
    float* __restrict__ buf, float* __restrict__ ctx)
{
    __shared__ float sred[4];
    const int b = blockIdx.x, tid = threadIdx.x;
    float* p = buf + (size_t)b * SS;

    float z[16];
    #pragma unroll
    for (int j = 0; j < 16; ++j) z[j] = p[tid + j * 256] * 0.5f;

    float m = -1e30f;
    #pragma unroll
    for (int j = 0; j < 16; ++j) m = fmaxf(m, z[j]);
    #pragma unroll
    for (int o = 1; o < 64; o <<= 1) m = fmaxf(m, __shfl_xor(m, o));
    if ((tid & 63) == 0) sred[tid >> 6] = m;
    __syncthreads();
    m = fmaxf(fmaxf(sred[0], sred[1]), fmaxf(sred[2], sred[3]));
    __syncthreads();
    #pragma unroll
    for (int j = 0; j < 16; ++j) z[j] -= m;

    float lo = -1.0f, hi = 0.0f;
    for (int it = 0; it < 35; ++it) {
        float tau = 0.5f * (lo + hi);
        float s = 0.0f;
        #pragma unroll
        for (int j = 0; j < 16; ++j) {
            float d = fmaxf(z[j] - tau, 0.0f);
            s = fmaf(d, d, s);
        }
        #pragma unroll
        for (int o = 1; o < 64; o <<= 1) s += __shfl_xor(s, o);
        if ((tid & 63) == 0) sred[tid >> 6] = s;
        __syncthreads();
        s = sred[0] + sred[1] + sred[2] + sred[3];
        __syncthreads();
        if (s >= 1.0f) lo = tau; else hi = tau;
    }
    const float tau = 0.5f * (lo + hi);

    #pragma unroll
    for (int j = 0; j < 16; ++j) {
        float d = fmaxf(z[j] - tau, 0.0f);
        p[tid + j * 256] = d * d;
    }
    ctx[b * HH + tid] = 0.0f;
}

// ---------------------------------------------------------------------------
// K3: context[b,h] += sum_s X[b,s,h] * w[b,s]; entmax sparsity -> skip zeros
// ---------------------------------------------------------------------------
__global__ __launch_bounds__(256) void context_kernel(
    const float* __restrict__ X, const float* __restrict__ w,
    float* __restrict__ ctx)
{
    const int b  = blockIdx.y;
    const int s0 = blockIdx.x * 128;
    const int h  = threadIdx.x;

    __shared__ float ws_[128];
    __shared__ int nzflag;
    if (h == 0) nzflag = 0;
    __syncthreads();
    if (h < 128) {
        float v = w[(size_t)b * SS + s0 + h];
        ws_[h] = v;
        if (v > 0.0f) nzflag = 1;
    }
    __syncthreads();
    if (!nzflag) return;

    float acc = 0.0f;
    const float* xp = X + ((size_t)b * SS + s0) * HH + h;
    #pragma unroll 4
    for (int i = 0; i < 128; ++i) {
        float wv = ws_[i];
        if (wv != 0.0f) acc = fmaf(xp[(size_t)i * HH], wv, acc);
    }
    atomicAdd(&ctx[b * HH + h], acc);
}

extern "C" void kernel_launch(void* const* d_in, const int* in_sizes, int n_in,
                              void* d_out, int out_size, void* d_ws, size_t ws_size,
                              hipStream_t stream) {
    const float* X  = (const float*)d_in[0];
    const float* W1 = (const float*)d_in[1];
    const float* b1 = (const float*)d_in[2];
    const float* W2 = (const float*)d_in[3];
    const float* b2 = (const float*)d_in[4];

    float* out = (float*)d_out;
    float* ctx = out;            // [64*256]
    float* wts = out + BB * HH;  // [64*4096] scores -> weights
    _Float16* Wt = (_Float16*)d_ws;  // [128][256] f16, 64 KB

    convert_w1<<<AA, HH, 0, stream>>>(W1, Wt);
    score_nsplit<<<(BB * SS) / 32, 256, 0, stream>>>(X, Wt, b1, W2, b2, wts);
    entmax_kernel<<<BB, 256, 0, stream>>>(wts, ctx);
    context_kernel<<<dim3(SS / 128, BB), 256, 0, stream>>>(X, wts, ctx);
}

// Round 6
// 442.027 us; speedup vs baseline: 1.2962x; 1.1366x over previous
//
#include <hip/hip_runtime.h>
#include <hip/hip_bf16.h>

#define BB 64
#define SS 4096
#define HH 256
#define AA 128

typedef _Float16 half8v __attribute__((ext_vector_type(8)));
typedef float floatx16 __attribute__((ext_vector_type(16)));

__device__ __forceinline__ float fast_tanh(float x) {
    float xc = fminf(fmaxf(x, -9.0f), 9.0f);
    float e = __expf(2.0f * xc);
    return 1.0f - __fdividef(2.0f, e + 1.0f);
}

// ---------------------------------------------------------------------------
// K0: W1 [H=256][A=128] fp32  ->  Wt [A=128][H=256] f16 (transposed) in d_ws
// ---------------------------------------------------------------------------
__global__ void convert_w1(const float* __restrict__ W1, _Float16* __restrict__ Wt) {
    int n = blockIdx.x;    // 0..127 (A)
    int k = threadIdx.x;   // 0..255 (H)
    Wt[n * HH + k] = (_Float16)W1[k * AA + n];
}

// ---------------------------------------------------------------------------
// K1: scores = tanh(X@W1 + b1)@W2 + b2 — B fully LDS-resident streaming MFMA.
// Entire W1^T (f16, 64 KB) staged once per block into LDS in MFMA B-frag
// order: frag (kh = k2*2+lhalf, n) lives at Bs + (kh*128+n)*8 f16 (16 B).
// After ONE barrier, each wave independently processes 4 tiles of 32 rows x
// 128 cols: per k-step {2 global float4 A loads, pk-cvt, 4 ds_read_b128,
// 4 MFMA}. acc = 4 x floatx16, static indices only (no spill). B from LDS
// means in-loop B reads cost ~12 cyc, not 200-900 (the R3/R5 failure).
// A layout: m=lane&31, k=(lane>>5)*8+j.  B layout: n=lane&31, k=(lane>>5)*8+j.
// C layout (32x32): col=lane&31, row=(r&3)+8*(r>>2)+4*(lane>>5)  [verified].
// ---------------------------------------------------------------------------
__global__ __launch_bounds__(256, 2) void score_ldsb(
    const float* __restrict__ X,        // [B*S, H]
    const _Float16* __restrict__ Wt,    // [A, H] f16
    const float* __restrict__ b1,       // [A]
    const float* __restrict__ W2,       // [A]
    const float* __restrict__ b2,       // [1]
    float* __restrict__ scores)         // [B*S]
{
    __shared__ _Float16 Bs[32768];      // 64 KB

    const int tid   = threadIdx.x;
    const int wid   = tid >> 6;
    const int lane  = tid & 63;
    const int lrow  = lane & 31;
    const int lhalf = lane >> 5;

    // --- stage Wt -> LDS in B-frag order (one time) ---
    #pragma unroll
    for (int i = 0; i < 16; ++i) {
        int f = tid + i * 256;             // frag id: (kh*128 + n), 0..4095
        int n = f & 127, kh = f >> 7;      // kh = k2*2 + lhalf
        *(uint4*)(Bs + (size_t)f * 8) = *(const uint4*)(Wt + (size_t)n * HH + kh * 8);
    }
    __syncthreads();

    // per-lane column constants (col = nt*32 + lrow)
    float cb1[4], cw2[4];
    #pragma unroll
    for (int nt = 0; nt < 4; ++nt) {
        cb1[nt] = b1[nt * 32 + lrow];
        cw2[nt] = W2[nt * 32 + lrow];
    }
    const float bias2 = b2[0];

    const int gw = blockIdx.x * 4 + wid;   // global wave id, 0..2047

    #pragma unroll 1
    for (int t = 0; t < 4; ++t) {
        const int m0 = (gw * 4 + t) * 32;
        const float* xp = X + (size_t)(m0 + lrow) * HH + lhalf * 8;

        floatx16 acc[4];
        #pragma unroll
        for (int nt = 0; nt < 4; ++nt)
            #pragma unroll
            for (int r = 0; r < 16; ++r) acc[nt][r] = 0.0f;

        #pragma unroll
        for (int k2 = 0; k2 < 16; ++k2) {
            float4 v0 = *(const float4*)(xp + k2 * 16);
            float4 v1 = *(const float4*)(xp + k2 * 16 + 4);
            half8v a;
            a[0] = (_Float16)v0.x; a[1] = (_Float16)v0.y;
            a[2] = (_Float16)v0.z; a[3] = (_Float16)v0.w;
            a[4] = (_Float16)v1.x; a[5] = (_Float16)v1.y;
            a[6] = (_Float16)v1.z; a[7] = (_Float16)v1.w;
            const _Float16* bp = Bs + ((size_t)(k2 * 2 + lhalf) * 128 + lrow) * 8;
            #pragma unroll
            for (int nt = 0; nt < 4; ++nt) {
                half8v b = *(const half8v*)(bp + nt * 32 * 8);
                acc[nt] = __builtin_amdgcn_mfma_f32_32x32x16_f16(a, b, acc[nt], 0, 0, 0);
            }
        }

        // wave-local epilogue: tanh + dot(W2), reduce 32-lane halves
        #pragma unroll
        for (int r = 0; r < 16; ++r) {
            float v = 0.0f;
            #pragma unroll
            for (int nt = 0; nt < 4; ++nt)
                v += fast_tanh(acc[nt][r] + cb1[nt]) * cw2[nt];
            #pragma unroll
            for (int o = 1; o < 32; o <<= 1) v += __shfl_xor(v, o);
            if (lrow == 0)
                scores[m0 + (r & 3) + 8 * (r >> 2) + 4 * lhalf] = v + bias2;
        }
    }
}

// ---------------------------------------------------------------------------
// K2: entmax-1.5 over S per batch row via bisection on tau.
// In-place scores -> weights; zero-inits ctx.
// ---------------------------------------------------------------------------
__global__ __launch_bounds__(256) void entmax_kernel(
    float* __restrict__ buf, float* __restrict__ ctx)
{
    __shared__ float sred[4];
    const int b = blockIdx.x, tid = threadIdx.x;
    float* p = buf + (size_t)b * SS;

    float z[16];
    #pragma unroll
    for (int j = 0; j < 16; ++j) z[j] = p[tid + j * 256] * 0.5f;

    float m = -1e30f;
    #pragma unroll
    for (int j = 0; j < 16; ++j) m = fmaxf(m, z[j]);
    #pragma unroll
    for (int o = 1; o < 64; o <<= 1) m = fmaxf(m, __shfl_xor(m, o));
    if ((tid & 63) == 0) sred[tid >> 6] = m;
    __syncthreads();
    m = fmaxf(fmaxf(sred[0], sred[1]), fmaxf(sred[2], sred[3]));
    __syncthreads();
    #pragma unroll
    for (int j = 0; j < 16; ++j) z[j] -= m;

    float lo = -1.0f, hi = 0.0f;
    for (int it = 0; it < 35; ++it) {
        float tau = 0.5f * (lo + hi);
        float s = 0.0f;
        #pragma unroll
        for (int j = 0; j < 16; ++j) {
            float d = fmaxf(z[j] - tau, 0.0f);
            s = fmaf(d, d, s);
        }
        #pragma unroll
        for (int o = 1; o < 64; o <<= 1) s += __shfl_xor(s, o);
        if ((tid & 63) == 0) sred[tid >> 6] = s;
        __syncthreads();
        s = sred[0] + sred[1] + sred[2] + sred[3];
        __syncthreads();
        if (s >= 1.0f) lo = tau; else hi = tau;
    }
    const float tau = 0.5f * (lo + hi);

    #pragma unroll
    for (int j = 0; j < 16; ++j) {
        float d = fmaxf(z[j] - tau, 0.0f);
        p[tid + j * 256] = d * d;
    }
    ctx[b * HH + tid] = 0.0f;
}

// ---------------------------------------------------------------------------
// K3: context[b,h] += sum_s X[b,s,h] * w[b,s]; entmax sparsity -> skip zeros
// ---------------------------------------------------------------------------
__global__ __launch_bounds__(256) void context_kernel(
    const float* __restrict__ X, const float* __restrict__ w,
    float* __restrict__ ctx)
{
    const int b  = blockIdx.y;
    const int s0 = blockIdx.x * 128;
    const int h  = threadIdx.x;

    __shared__ float ws_[128];
    __shared__ int nzflag;
    if (h == 0) nzflag = 0;
    __syncthreads();
    if (h < 128) {
        float v = w[(size_t)b * SS + s0 + h];
        ws_[h] = v;
        if (v > 0.0f) nzflag = 1;
    }
    __syncthreads();
    if (!nzflag) return;

    float acc = 0.0f;
    const float* xp = X + ((size_t)b * SS + s0) * HH + h;
    #pragma unroll 4
    for (int i = 0; i < 128; ++i) {
        float wv = ws_[i];
        if (wv != 0.0f) acc = fmaf(xp[(size_t)i * HH], wv, acc);
    }
    atomicAdd(&ctx[b * HH + h], acc);
}

extern "C" void kernel_launch(void* const* d_in, const int* in_sizes, int n_in,
                              void* d_out, int out_size, void* d_ws, size_t ws_size,
                              hipStream_t stream) {
    const float* X  = (const float*)d_in[0];
    const float* W1 = (const float*)d_in[1];
    const float* b1 = (const float*)d_in[2];
    const float* W2 = (const float*)d_in[3];
    const float* b2 = (const float*)d_in[4];

    float* out = (float*)d_out;
    float* ctx = out;            // [64*256]
    float* wts = out + BB * HH;  // [64*4096] scores -> weights
    _Float16* Wt = (_Float16*)d_ws;  // [128][256] f16, 64 KB

    convert_w1<<<AA, HH, 0, stream>>>(W1, Wt);
    score_ldsb<<<512, 256, 0, stream>>>(X, Wt, b1, W2, b2, wts);
    entmax_kernel<<<BB, 256, 0, stream>>>(wts, ctx);
    context_kernel<<<dim3(SS / 128, BB), 256, 0, stream>>>(X, wts, ctx);
}

// Round 7
// 406.571 us; speedup vs baseline: 1.4093x; 1.0872x over previous
//
#include <hip/hip_runtime.h>
#include <hip/hip_bf16.h>

#define BB 64
#define SS 4096
#define HH 256
#define AA 128
#define MT 128
#define BK 32
#define NCHUNK (HH / BK)   // 8

typedef _Float16 half8v __attribute__((ext_vector_type(8)));
typedef float floatx16 __attribute__((ext_vector_type(16)));

__device__ __forceinline__ float fast_tanh(float x) {
    float xc = fminf(fmaxf(x, -9.0f), 9.0f);
    float e = __expf(2.0f * xc);
    return 1.0f - __fdividef(2.0f, e + 1.0f);
}

__device__ __forceinline__ void async16(const void* g, void* l) {
    __builtin_amdgcn_global_load_lds(
        (const __attribute__((address_space(1))) unsigned int*)g,
        (__attribute__((address_space(3))) unsigned int*)l, 16, 0, 0);
}

// ---------------------------------------------------------------------------
// K0: W1 [H=256][A=128] fp32  ->  Wt [A=128][H=256] f16 (transposed) in d_ws
// ---------------------------------------------------------------------------
__global__ void convert_w1(const float* __restrict__ W1, _Float16* __restrict__ Wt) {
    int n = blockIdx.x;    // 0..127 (A)
    int k = threadIdx.x;   // 0..255 (H)
    Wt[n * HH + k] = (_Float16)W1[k * AA + n];
}

// ---------------------------------------------------------------------------
// K1: scores = tanh(X@W1+b1)@W2+b2 — DMA-staged, XOR-swizzled, double-buffered.
// Why: MFMA A-frag layout (m=lane&31) makes direct global A-loads a 32-line
// gather (R3/R5/R6 all ~27% stream BW). So stage coalesced via
// global_load_lds (width 16, zero VALU), swizzle granules to keep the
// strided fragment reads bank-conflict-free (no padding allowed: DMA writes
// lane i -> base + i*16).
//   X granule (r,g) g=0..7 (16B) -> LDS slot r*8 + (g ^ (r&7))
//   B granule (n,gb) gb=0..3    -> LDS slot n*4 + (gb ^ (n&3))
// Block = 4 waves: wave (rh=wid>>1, ch=wid&1) computes rows rh*64+{0,32},
// cols ch*64+{0,32} as 2x2 mfma_f32_32x32x16_f16, fp32->f16 cvt at frag read.
// C layout (32x32): col=lane&31, row=(r&3)+8*(r>>2)+4*(lane>>5)  [verified].
// ---------------------------------------------------------------------------
__global__ __launch_bounds__(256, 3) void score_dma(
    const float* __restrict__ X,        // [B*S, H]
    const _Float16* __restrict__ Wt,    // [A, H] f16
    const float* __restrict__ b1,       // [A]
    const float* __restrict__ W2,       // [A]
    const float* __restrict__ b2,       // [1]
    float* __restrict__ scores)         // [B*S]
{
    __shared__ float    Xs[2][4096];     // 2 x 16 KB (128 rows x 32 k fp32)
    __shared__ _Float16 Bsh[2][4096];    // 2 x  8 KB (128 cols x 32 k f16)
    __shared__ float    red[2][128];     // epilogue combine

    const int tid   = threadIdx.x;
    const int wid   = tid >> 6;
    const int lane  = tid & 63;
    const int lrow  = lane & 31;
    const int lhalf = lane >> 5;
    const int rh    = wid >> 1;
    const int ch    = wid & 1;
    const int m0    = blockIdx.x * MT;

    // DMA lane geometry (i-independent parts)
    const int xr = tid >> 3;                       // row slot 0..31 (+ i*32)
    const int xg = (tid & 7) ^ (xr & 7);           // swizzled granule
    const float* xgp = X + (size_t)(m0 + xr) * HH + xg * 4;
    const int bn = tid >> 2;                       // col slot 0..63 (+ i*64)
    const int bg = (tid & 3) ^ (bn & 3);
    const _Float16* bgp = Wt + (size_t)bn * HH + bg * 8;

    // per-lane epilogue constants
    float cb1[2], cw2[2];
    #pragma unroll
    for (int ct = 0; ct < 2; ++ct) {
        int col = ch * 64 + ct * 32 + lrow;
        cb1[ct] = b1[col];
        cw2[ct] = W2[col];
    }

    floatx16 acc[2][2];
    #pragma unroll
    for (int rt = 0; rt < 2; ++rt)
        #pragma unroll
        for (int ct = 0; ct < 2; ++ct)
            #pragma unroll
            for (int r = 0; r < 16; ++r) acc[rt][ct][r] = 0.0f;

    // --- stage chunk 0 ---
    #pragma unroll
    for (int i = 0; i < 4; ++i)
        async16(xgp + (size_t)i * 32 * HH, (char*)&Xs[0][0] + i * 4096 + wid * 1024);
    #pragma unroll
    for (int i = 0; i < 2; ++i)
        async16(bgp + (size_t)i * 64 * HH, (char*)&Bsh[0][0] + i * 4096 + wid * 1024);
    __syncthreads();

    #pragma unroll 1
    for (int c = 0; c < NCHUNK; ++c) {
        // prefetch chunk c+1 into the other buffer
        if (c + 1 < NCHUNK) {
            const int k0 = (c + 1) * BK;
            const int nb = (c + 1) & 1;
            #pragma unroll
            for (int i = 0; i < 4; ++i)
                async16(xgp + (size_t)i * 32 * HH + k0,
                        (char*)&Xs[nb][0] + i * 4096 + wid * 1024);
            #pragma unroll
            for (int i = 0; i < 2; ++i)
                async16(bgp + (size_t)i * 64 * HH + k0,
                        (char*)&Bsh[nb][0] + i * 4096 + wid * 1024);
        }
        // compute chunk c
        const float*    xb = &Xs[c & 1][0];
        const _Float16* bb = &Bsh[c & 1][0];
        #pragma unroll
        for (int s = 0; s < 2; ++s) {
            half8v bf[2];
            #pragma unroll
            for (int ct = 0; ct < 2; ++ct) {
                int n = ch * 64 + ct * 32 + lrow;
                int idx = n * 4 + ((s * 2 + lhalf) ^ (n & 3));
                bf[ct] = *(const half8v*)(bb + (size_t)idx * 8);
            }
            #pragma unroll
            for (int rt = 0; rt < 2; ++rt) {
                int r  = rh * 64 + rt * 32 + lrow;
                int g0 = s * 4 + lhalf * 2;
                int i0 = r * 8 + (g0 ^ (r & 7));
                int i1 = r * 8 + ((g0 + 1) ^ (r & 7));
                float4 va = *(const float4*)(xb + (size_t)i0 * 4);
                float4 vb = *(const float4*)(xb + (size_t)i1 * 4);
                half8v a;
                a[0] = (_Float16)va.x; a[1] = (_Float16)va.y;
                a[2] = (_Float16)va.z; a[3] = (_Float16)va.w;
                a[4] = (_Float16)vb.x; a[5] = (_Float16)vb.y;
                a[6] = (_Float16)vb.z; a[7] = (_Float16)vb.w;
                acc[rt][0] = __builtin_amdgcn_mfma_f32_32x32x16_f16(a, bf[0], acc[rt][0], 0, 0, 0);
                acc[rt][1] = __builtin_amdgcn_mfma_f32_32x32x16_f16(a, bf[1], acc[rt][1], 0, 0, 0);
            }
        }
        if (c + 1 < NCHUNK) __syncthreads();
    }

    // --- epilogue: tanh + dot(W2); reduce over this wave's 64 cols, combine ---
    #pragma unroll
    for (int rt = 0; rt < 2; ++rt) {
        #pragma unroll
        for (int r = 0; r < 16; ++r) {
            float v = fast_tanh(acc[rt][0][r] + cb1[0]) * cw2[0]
                    + fast_tanh(acc[rt][1][r] + cb1[1]) * cw2[1];
            #pragma unroll
            for (int o = 1; o < 32; o <<= 1) v += __shfl_xor(v, o);  // halves independent
            if (lrow == 0)
                red[ch][rh * 64 + rt * 32 + (r & 3) + 8 * (r >> 2) + 4 * lhalf] = v;
        }
    }
    __syncthreads();
    if (tid < MT)
        scores[m0 + tid] = b2[0] + red[0][tid] + red[1][tid];
}

// ---------------------------------------------------------------------------
// K2: entmax-1.5 over S per batch row via bisection on tau.
// In-place scores -> weights; zero-inits ctx.
// ---------------------------------------------------------------------------
__global__ __launch_bounds__(256) void entmax_kernel(
    float* __restrict__ buf, float* __restrict__ ctx)
{
    __shared__ float sred[4];
    const int b = blockIdx.x, tid = threadIdx.x;
    float* p = buf + (size_t)b * SS;

    float z[16];
    #pragma unroll
    for (int j = 0; j < 16; ++j) z[j] = p[tid + j * 256] * 0.5f;

    float m = -1e30f;
    #pragma unroll
    for (int j = 0; j < 16; ++j) m = fmaxf(m, z[j]);
    #pragma unroll
    for (int o = 1; o < 64; o <<= 1) m = fmaxf(m, __shfl_xor(m, o));
    if ((tid & 63) == 0) sred[tid >> 6] = m;
    __syncthreads();
    m = fmaxf(fmaxf(sred[0], sred[1]), fmaxf(sred[2], sred[3]));
    __syncthreads();
    #pragma unroll
    for (int j = 0; j < 16; ++j) z[j] -= m;

    float lo = -1.0f, hi = 0.0f;
    for (int it = 0; it < 35; ++it) {
        float tau = 0.5f * (lo + hi);
        float s = 0.0f;
        #pragma unroll
        for (int j = 0; j < 16; ++j) {
            float d = fmaxf(z[j] - tau, 0.0f);
            s = fmaf(d, d, s);
        }
        #pragma unroll
        for (int o = 1; o < 64; o <<= 1) s += __shfl_xor(s, o);
        if ((tid & 63) == 0) sred[tid >> 6] = s;
        __syncthreads();
        s = sred[0] + sred[1] + sred[2] + sred[3];
        __syncthreads();
        if (s >= 1.0f) lo = tau; else hi = tau;
    }
    const float tau = 0.5f * (lo + hi);

    #pragma unroll
    for (int j = 0; j < 16; ++j) {
        float d = fmaxf(z[j] - tau, 0.0f);
        p[tid + j * 256] = d * d;
    }
    ctx[b * HH + tid] = 0.0f;
}

// ---------------------------------------------------------------------------
// K3: context[b,h] += sum_s X[b,s,h] * w[b,s]; entmax sparsity -> skip zeros
// ---------------------------------------------------------------------------
__global__ __launch_bounds__(256) void context_kernel(
    const float* __restrict__ X, const float* __restrict__ w,
    float* __restrict__ ctx)
{
    const int b  = blockIdx.y;
    const int s0 = blockIdx.x * 128;
    const int h  = threadIdx.x;

    __shared__ float ws_[128];
    __shared__ int nzflag;
    if (h == 0) nzflag = 0;
    __syncthreads();
    if (h < 128) {
        float v = w[(size_t)b * SS + s0 + h];
        ws_[h] = v;
        if (v > 0.0f) nzflag = 1;
    }
    __syncthreads();
    if (!nzflag) return;

    float acc = 0.0f;
    const float* xp = X + ((size_t)b * SS + s0) * HH + h;
    #pragma unroll 4
    for (int i = 0; i < 128; ++i) {
        float wv = ws_[i];
        if (wv != 0.0f) acc = fmaf(xp[(size_t)i * HH], wv, acc);
    }
    atomicAdd(&ctx[b * HH + h], acc);
}

extern "C" void kernel_launch(void* const* d_in, const int* in_sizes, int n_in,
                              void* d_out, int out_size, void* d_ws, size_t ws_size,
                              hipStream_t stream) {
    const float* X  = (const float*)d_in[0];
    const float* W1 = (const float*)d_in[1];
    const float* b1 = (const float*)d_in[2];
    const float* W2 = (const float*)d_in[3];
    const float* b2 = (const float*)d_in[4];

    float* out = (float*)d_out;
    float* ctx = out;            // [64*256]
    float* wts = out + BB * HH;  // [64*4096] scores -> weights
    _Float16* Wt = (_Float16*)d_ws;  // [128][256] f16, 64 KB

    convert_w1<<<AA, HH, 0, stream>>>(W1, Wt);
    score_dma<<<(BB * SS) / MT, 256, 0, stream>>>(X, Wt, b1, W2, b2, wts);
    entmax_kernel<<<BB, 256, 0, stream>>>(wts, ctx);
    context_kernel<<<dim3(SS / 128, BB), 256, 0, stream>>>(X, wts, ctx);
}